// Round 11
// baseline (388.399 us; speedup 1.0000x reference)
//
#include <hip/hip_runtime.h>

#define DIN 1024
#define DE  1024
#define SEQ 2048
#define NB  8

typedef __bf16 bf16x8 __attribute__((ext_vector_type(8)));
typedef float  f32x4  __attribute__((ext_vector_type(4)));
typedef unsigned short u16;
typedef u16 u16x8 __attribute__((ext_vector_type(8)));
typedef u16 u16x4 __attribute__((ext_vector_type(4)));

__device__ __forceinline__ u16 f2bf(float f) {
  unsigned u = __builtin_bit_cast(unsigned, f);
  return (u16)((u + 0x7FFFu + ((u >> 16) & 1u)) >> 16);
}
__device__ __forceinline__ float bf2f(u16 h) {
  return __builtin_bit_cast(float, (unsigned)h << 16);
}

typedef __attribute__((address_space(1))) const unsigned char g_u8;
typedef __attribute__((address_space(3))) unsigned char l_u8;
__device__ __forceinline__ void gload16(const void* g, void* l) {
  __builtin_amdgcn_global_load_lds((g_u8*)g, (l_u8*)l, 16, 0, 0);
}

// ---------------- convert fp32 -> bf16 (vectorized) ----------------
__global__ __launch_bounds__(256) void cvt_f32_bf16(const float* __restrict__ in,
                                                    u16* __restrict__ out, int n4) {
  int i = blockIdx.x * 256 + threadIdx.x;
  if (i >= n4) return;
  float4 v = ((const float4*)in)[i];
  u16x4 o;
  o[0] = f2bf(v.x); o[1] = f2bf(v.y); o[2] = f2bf(v.z); o[3] = f2bf(v.w);
  ((u16x4*)out)[i] = o;
}

// ---------------- transpose W [K=1024][N=1024] fp32 -> Wt [N][K] bf16 ----------------
__global__ __launch_bounds__(256) void transpose_w(const float* __restrict__ W,
                                                   u16* __restrict__ Wt) {
  __shared__ float t[32][33];
  const int tx = threadIdx.x, ty = threadIdx.y;
  const int bx = blockIdx.x * 32, by = blockIdx.y * 32;
#pragma unroll
  for (int i = 0; i < 4; ++i)
    t[ty + i * 8][tx] = W[(size_t)(by + ty + i * 8) * 1024 + bx + tx];
  __syncthreads();
#pragma unroll
  for (int i = 0; i < 4; ++i)
    Wt[(size_t)(bx + ty + i * 8) * 1024 + by + tx] = f2bf(t[tx][ty + i * 8]);
}

// ---------------- in-place row softmax on bf16 [rows][2048] ----------------
__global__ __launch_bounds__(256) void softmax_rows_bf16(u16* __restrict__ P) {
  const size_t row = blockIdx.x;
  u16* pr = P + row * 2048 + (size_t)threadIdx.x * 8;
  u16x8 v = *(const u16x8*)pr;
  float x[8];
#pragma unroll
  for (int j = 0; j < 8; ++j) x[j] = bf2f(v[j]);
  float m = x[0];
#pragma unroll
  for (int j = 1; j < 8; ++j) m = fmaxf(m, x[j]);
#pragma unroll
  for (int off = 32; off; off >>= 1) m = fmaxf(m, __shfl_xor(m, off));
  __shared__ float rm[4], rs[4];
  const int lane = threadIdx.x & 63, wid = threadIdx.x >> 6;
  if (lane == 0) rm[wid] = m;
  __syncthreads();
  m = fmaxf(fmaxf(rm[0], rm[1]), fmaxf(rm[2], rm[3]));
  float s = 0.f;
#pragma unroll
  for (int j = 0; j < 8; ++j) { x[j] = __expf(x[j] - m); s += x[j]; }
#pragma unroll
  for (int off = 32; off; off >>= 1) s += __shfl_xor(s, off);
  if (lane == 0) rs[wid] = s;
  __syncthreads();
  s = (rs[0] + rs[1]) + (rs[2] + rs[3]);
  const float inv = 1.f / s;
  u16x8 o;
#pragma unroll
  for (int j = 0; j < 8; ++j) o[j] = f2bf(x[j] * inv);
  *(u16x8*)pr = o;
}

// ====== register-pipelined GEMM: C = A[M,K]*Bt[N,K]^T, reads one tile AHEAD ======
// 256x256 tile, 8 waves (2Mx4N, wave 128x64), BK=32, QUAD-buffered LDS (128 KB),
// staging 3 tiles ahead, counted vmcnt(4). Two named operand register sets:
// body t = { stage(t+3); ds_read tile t+1 -> idle set; sched_barrier;
//            32 MFMA on current set; counted vmcnt; barrier }.
// The reads' completion-wait (compiler lgkmcnt) lands before the NEXT body's
// MFMA, so the LDS pipe streams concurrently with this body's MFMA pipe —
// the overlap every lockstep schedule (r5-r10, 35-42% MfmaUtil) lacked.
// Race: stage(t+3) overwrites buf[(t-1)&3]; its register-reads completed before
// body (t-1)'s end barrier. Swizzle: phys kslot = gk^((row>>1)&3) (0 conflicts,
// r7/r10), staged linearly via inverse-swizzled global source.
// OMODE: 0=fp32 out, 1=bf16 out, 3=QKV-split (col<1024->C0, <2048->C1, else
// Vt-scatter C2[b][col][s]).
#define READF(BUFI, AV, BV)                                                   \
  {                                                                           \
    const char* _b = lds + (BUFI) * 32768;                                    \
    _Pragma("unroll") for (int n_ = 0; n_ < 4; ++n_)                          \
        BV[n_] = *(const bf16x8*)(_b + boffB + n_ * 1024);                    \
    _Pragma("unroll") for (int m_ = 0; m_ < 8; ++m_)                          \
        AV[m_] = *(const bf16x8*)(_b + aoffB + m_ * 1024);                    \
  }
#define MFMAF(AV, BV)                                                         \
  {                                                                           \
    __builtin_amdgcn_s_setprio(1);                                            \
    _Pragma("unroll") for (int m_ = 0; m_ < 8; ++m_)                          \
        _Pragma("unroll") for (int n_ = 0; n_ < 4; ++n_)                      \
            acc[m_][n_] = __builtin_amdgcn_mfma_f32_16x16x32_bf16(            \
                AV[m_], BV[n_], acc[m_][n_], 0, 0, 0);                        \
    __builtin_amdgcn_s_setprio(0);                                            \
  }

template <int OMODE, bool HAS_BIAS>
__global__ __launch_bounds__(512, 2) void gemmrp(
    const u16* __restrict__ A, const u16* __restrict__ Bt, void* __restrict__ C0,
    u16* __restrict__ C1, u16* __restrict__ C2, const float* __restrict__ b0,
    const float* __restrict__ b1, const float* __restrict__ b2,
    int M, int Nout, int K, size_t sA, size_t sB, size_t sC, float scale) {
  __shared__ __align__(16) char lds[4 * 32768];
  const int tid = threadIdx.x, lane = tid & 63, wid = tid >> 6;
  const int wm = wid >> 2, wn = wid & 3;
  const int lane15 = lane & 15, gk = lane >> 4;

  // bijective XCD-aware block remap (3D)
  const int gx = gridDim.x, gy = gridDim.y;
  int lin = blockIdx.x + gx * (blockIdx.y + gy * blockIdx.z);
  const int nwg = gx * gy * (int)gridDim.z;
  const int q = nwg >> 3, r8 = nwg & 7;
  const int xcd = lin & 7, idx = lin >> 3;
  lin = (xcd < r8 ? xcd * (q + 1) : r8 * (q + 1) + (xcd - r8) * q) + idx;
  const int bz = lin / (gx * gy);
  const int rem = lin - bz * (gx * gy);
  const int by = rem / gx, bx = rem - (rem / gx) * gx;

  const char* Ag = (const char*)(A + (size_t)bz * sA + (size_t)by * 256 * K);
  const char* Bg = (const char*)(Bt + (size_t)bz * sB + (size_t)bx * 256 * K);
  const size_t Kb = (size_t)K * 2;

  // staging: linear LDS slot ls = j*512+tid; phys row pr=ls>>2, slot ps=ls&3
  // holds logical kslot g = ps ^ ((pr>>1)&3). 4 gloads/thread per 32-K tile.
  const char* sa[2];
  const char* sb[2];
  int dA[2], dB[2];
#pragma unroll
  for (int j = 0; j < 2; ++j) {
    const int ls = j * 512 + tid, pr = ls >> 2, ps = ls & 3;
    const int g = ps ^ ((pr >> 1) & 3);
    sa[j] = Ag + (size_t)pr * Kb + g * 16;
    sb[j] = Bg + (size_t)pr * Kb + g * 16;
    dA[j] = ls * 16;
    dB[j] = 16384 + ls * 16;
  }
  auto stage = [&](int b) {
    char* base = lds + b * 32768;
#pragma unroll
    for (int j = 0; j < 2; ++j) {
      gload16(sa[j], base + dA[j]);
      gload16(sb[j], base + dB[j]);
      sa[j] += 64; sb[j] += 64;
    }
  };

  // fragment read bases: swizzle term is m/n-independent ((r>>1)&3 depends only
  // on lane15>>1), so frag m/n = base + m*1024 / n*1024 (folds into ds offset).
  const int sw = (gk ^ ((lane15 >> 1) & 3)) << 4;
  const int aoffB = wm * 8192 + lane15 * 64 + sw;
  const int boffB = 16384 + wn * 4096 + lane15 * 64 + sw;

  f32x4 acc[8][4] = {};
  bf16x8 pa[8], pb[4], qa[8], qb[4];
  const int NT = K >> 5;  // NT even (K = 1024 or 2048)

  // prologue: stage tiles 0..2; wait t0,t1 landed (t2 in flight); read t0
  stage(0); stage(1); stage(2);
  asm volatile("s_waitcnt vmcnt(4)" ::: "memory");
  __builtin_amdgcn_s_barrier();
  __builtin_amdgcn_sched_barrier(0);
  READF(0, pa, pb);

  for (int t = 0; t < NT; t += 2) {
    // ---- body even: MFMA tile t (pa/pb); read t+1 -> qa/qb; stage t+3 ----
    if (t + 3 < NT) stage((t + 3) & 3);
    READF((t + 1) & 3, qa, qb);
    __builtin_amdgcn_sched_barrier(0);  // reads issue before MFMA burst
    MFMAF(pa, pb);
    if (t + 3 < NT) asm volatile("s_waitcnt vmcnt(4)" ::: "memory");
    else            asm volatile("s_waitcnt vmcnt(0)" ::: "memory");
    __builtin_amdgcn_s_barrier();
    __builtin_amdgcn_sched_barrier(0);
    // ---- body odd: MFMA tile t+1 (qa/qb); read t+2 -> pa/pb; stage t+4 ----
    if (t + 4 < NT) stage((t + 4) & 3);
    if (t + 2 < NT) READF((t + 2) & 3, pa, pb);
    __builtin_amdgcn_sched_barrier(0);
    MFMAF(qa, qb);
    if (t + 4 < NT) asm volatile("s_waitcnt vmcnt(4)" ::: "memory");
    else            asm volatile("s_waitcnt vmcnt(0)" ::: "memory");
    __builtin_amdgcn_s_barrier();
    __builtin_amdgcn_sched_barrier(0);
  }

  // epilogue: C layout col = lane&15, row = gk*4 + reg
  const int rbase = by * 256 + wm * 128 + (gk << 2);
  const int cbase = bx * 256 + wn * 64 + lane15;
#pragma unroll
  for (int m = 0; m < 8; ++m)
#pragma unroll
    for (int n = 0; n < 4; ++n) {
      const int col = cbase + n * 16;
      if (OMODE == 3) {
        // QKV merged: col region uniform per block (bx*256 chunks)
        u16* Cp; int ccol; const float* bp;
        if (col < 1024)      { Cp = (u16*)C0; ccol = col;        bp = b0; }
        else if (col < 2048) { Cp = C1;       ccol = col - 1024; bp = b1; }
        else                 { Cp = C2;       ccol = col - 2048; bp = b2; }
        const float bval = bp[ccol];
#pragma unroll
        for (int r = 0; r < 4; ++r) {
          const int rowg = rbase + m * 16 + r;
          const float v = acc[m][n][r] + bval;
          if (col < 2048)
            Cp[(size_t)rowg * 1024 + ccol] = f2bf(v);
          else  // V: write transposed Vt[b][col][s]
            Cp[(size_t)(rowg >> 11) * ((size_t)DE * SEQ) +
               (size_t)ccol * SEQ + (rowg & 2047)] = f2bf(v);
        }
      } else {
        const float bval = HAS_BIAS ? b0[col] : 0.f;
#pragma unroll
        for (int r = 0; r < 4; ++r) {
          const int rowg = rbase + m * 16 + r;
          const float v = acc[m][n][r] * scale + bval;
          if (OMODE == 0)
            ((float*)C0)[(size_t)bz * sC + (size_t)rowg * Nout + col] = v;
          else
            ((u16*)C0)[(size_t)bz * sC + (size_t)rowg * Nout + col] = f2bf(v);
        }
      }
    }
}

extern "C" void kernel_launch(void* const* d_in, const int* in_sizes, int n_in,
                              void* d_out, int out_size, void* d_ws, size_t ws_size,
                              hipStream_t stream) {
  const float* x  = (const float*)d_in[0];
  const float* Wq = (const float*)d_in[1];
  const float* bq = (const float*)d_in[2];
  const float* Wk = (const float*)d_in[3];
  const float* bk = (const float*)d_in[4];
  const float* Wv = (const float*)d_in[5];
  const float* bv = (const float*)d_in[6];
  const float* Wo = (const float*)d_in[7];
  const float* bo = (const float*)d_in[8];

  // workspace (bytes) — total 142,606,336. bf16 logits/P [8][2048][2048]
  // = 67,108,864 B live in d_out, dead before the final Wo GEMM overwrites it.
  const size_t NEED = 142606336;
  if (ws_size < NEED) return;
  char* ws = (char*)d_ws;
  u16* x_bf = (u16*)(ws);                   // 33,554,432
  u16* q_bf = (u16*)(ws + 33554432);        // 33,554,432 (Q; later attn output)
  u16* k_bf = (u16*)(ws + 67108864);        // 33,554,432
  u16* vt   = (u16*)(ws + 100663296);       // 33,554,432 (V^T per batch [d][s])
  u16* wt   = (u16*)(ws + 134217728);       // 8,388,608  (wqkv 6MB + wo 2MB)
  u16* lgP  = (u16*)d_out;                  // 67,108,864 (logits/P scratch)
  u16* wt_q = wt;
  u16* wt_k = wt + 1048576;
  u16* wt_v = wt + 2097152;
  u16* wt_o = wt + 3145728;

  dim3 tb(32, 8);
  const size_t sQ = (size_t)SEQ * DE;   // per-batch Q/K/attn/vt stride
  const size_t sL = (size_t)SEQ * SEQ;  // per-batch logits stride

  // 1. x -> bf16
  cvt_f32_bf16<<<16384, 256, 0, stream>>>(x, x_bf, (NB * SEQ * DIN) / 4);
  // 2. weight transposes (fp32 -> bf16, [K,N] -> [N,K]); wq|wk|wv contiguous
  transpose_w<<<dim3(32, 32), tb, 0, stream>>>(Wq, wt_q);
  transpose_w<<<dim3(32, 32), tb, 0, stream>>>(Wk, wt_k);
  transpose_w<<<dim3(32, 32), tb, 0, stream>>>(Wv, wt_v);
  transpose_w<<<dim3(32, 32), tb, 0, stream>>>(Wo, wt_o);
  // 3. merged QKV projection: [16384,1024] @ [3072,1024]^T, split epilogue
  gemmrp<3, true><<<dim3(12, 64, 1), 512, 0, stream>>>(x_bf, wt, q_bf, k_bf, vt,
      bq, bk, bv, 16384, 1024, 1024, 0, 0, 0, 1.f);
  // 4. logits = Q @ K^T * (1/32) -> bf16 in d_out, all batches (512 blocks)
  gemmrp<1, false><<<dim3(8, 8, 8), 512, 0, stream>>>(q_bf, k_bf, lgP,
      nullptr, nullptr, nullptr, nullptr, nullptr,
      2048, 2048, 1024, sQ, sQ, sL, 0.03125f);
  // 5. in-place row softmax over all 16384 rows
  softmax_rows_bf16<<<16384, 256, 0, stream>>>(lgP);
  // 6. values = P @ Vt^T -> overwrite q_bf (Q dead), 256 blocks, K=2048
  gemmrp<1, false><<<dim3(4, 8, 8), 512, 0, stream>>>(lgP, vt, q_bf,
      nullptr, nullptr, nullptr, nullptr, nullptr,
      2048, 1024, 2048, sL, sQ, sQ, 1.f);
  // 7. out = attn @ Wo + bo (fp32) -> d_out (overwrites dead P)
  gemmrp<0, true><<<dim3(4, 64, 1), 512, 0, stream>>>(q_bf, wt_o, d_out,
      nullptr, nullptr, bo, nullptr, nullptr,
      16384, 1024, 1024, 0, 0, 0, 1.f);

  (void)in_sizes; (void)n_in; (void)out_size; (void)ws_size;
}